// Round 2
// baseline (6149.489 us; speedup 1.0000x reference)
//
#include <hip/hip_runtime.h>
#include <hip/hip_bf16.h>

#define N_NODES   100000
#define N_EDGES   1600000
#define N_ETYPES  3
#define IN_FEATS  128
#define HEADS     4
#define OUT_FEATS 16
#define EDGE_FEATS 64
#define HD        64            // HEADS*OUT_FEATS
#define NEG_SLOPE 0.2f

// ---------------------------------------------------------------------------
// Kernel A: feat = x @ W   (f32), fused el/er per-node reductions.
// Block = 256 threads = 4 rows x 64 cols. W staged in LDS (32 KB).
// ---------------------------------------------------------------------------
__global__ __launch_bounds__(256) void feat_el_er_kernel(
    const float* __restrict__ x,
    const float* __restrict__ W,
    const float* __restrict__ attn_l,
    const float* __restrict__ attn_r,
    float* __restrict__ feat,
    float* __restrict__ el,
    float* __restrict__ er)
{
    __shared__ float Wl[IN_FEATS * HD];   // 32 KB
    __shared__ float Xl[4 * IN_FEATS];    //  2 KB

    const int t = threadIdx.x;

    // cooperative load W: 8192 f32 = 2048 float4; 8 per thread
    {
        const float4* Wg = (const float4*)W;
        float4* Ws = (float4*)Wl;
#pragma unroll
        for (int i = 0; i < 8; ++i) Ws[t + 256 * i] = Wg[t + 256 * i];
    }
    const int row0 = blockIdx.x * 4;
    // cooperative load 4 rows of x: 512 f32 = 128 float4
    {
        const float4* Xg = (const float4*)(x + (size_t)row0 * IN_FEATS);
        float4* Xs = (float4*)Xl;
        if (t < 128) Xs[t] = Xg[t];
    }
    __syncthreads();

    const int lr  = t >> 6;        // 0..3 local row (one wave per row)
    const int col = t & 63;        // 0..63 = h*16+d
    const int h   = col >> 4;
    const int d   = col & 15;

    const float* xr = &Xl[lr * IN_FEATS];
    float acc = 0.f;
#pragma unroll
    for (int k = 0; k < IN_FEATS; ++k)
        acc += xr[k] * Wl[k * HD + col];

    const int row = row0 + lr;
    feat[(size_t)row * HD + col] = acc;

    float cl = acc * attn_l[h * OUT_FEATS + d];
    float cr = acc * attn_r[h * OUT_FEATS + d];
#pragma unroll
    for (int m = 1; m < 16; m <<= 1) {
        cl += __shfl_xor(cl, m, 64);
        cr += __shfl_xor(cr, m, 64);
    }
    if (d == 0) {
        el[row * HEADS + h] = cl;
        er[row * HEADS + h] = cr;
    }
}

// ---------------------------------------------------------------------------
// Kernel B: ee[t,h] = sum_e (edge_emb[t] @ W_e)[h*64+e] * attn_e[h,e]
// grid = 12 (t,h) pairs, block = 64 (one wave), lane = e
// ---------------------------------------------------------------------------
__global__ __launch_bounds__(64) void ee_kernel(
    const float* __restrict__ edge_emb,
    const float* __restrict__ W_e,
    const float* __restrict__ attn_e,
    float* __restrict__ ee)
{
    const int b  = blockIdx.x;     // 0..11
    const int ty = b >> 2;
    const int h  = b & 3;
    const int e  = threadIdx.x;    // 0..63

    float ef = 0.f;
#pragma unroll
    for (int k = 0; k < EDGE_FEATS; ++k)
        ef += edge_emb[ty * EDGE_FEATS + k] *
              W_e[k * (HEADS * EDGE_FEATS) + h * EDGE_FEATS + e];
    float v = ef * attn_e[h * EDGE_FEATS + e];
#pragma unroll
    for (int m = 1; m < 64; m <<= 1) v += __shfl_xor(v, m, 64);
    if (e == 0) ee[ty * HEADS + h] = v;
}

// ---------------------------------------------------------------------------
// Kernel C: s = leaky(el[src]+er[dst]+ee[etype]) -> s_ws (sequential write);
//           z[dst,h] += exp(s).  One thread per (edge, head).
// exp(s) cannot overflow: |s| <= ~4 given the data scales, so skipping the
// segment_max shift is numerically safe in f32 (a = e/z is shift-invariant).
// ---------------------------------------------------------------------------
__global__ __launch_bounds__(256) void z_kernel(
    const int* __restrict__ src, const int* __restrict__ dst, const int* __restrict__ et,
    const float* __restrict__ el, const float* __restrict__ er, const float* __restrict__ ee,
    float* __restrict__ s_ws, float* __restrict__ z)
{
    const int t = blockIdx.x * 256 + threadIdx.x;
    const int e = t >> 2;
    const int h = t & 3;
    if (e >= N_EDGES) return;
    const int sn = src[e], dn = dst[e], ty = et[e];
    float s = el[sn * HEADS + h] + er[dn * HEADS + h] + ee[ty * HEADS + h];
    s = s > 0.f ? s : NEG_SLOPE * s;
    s_ws[(size_t)e * HEADS + h] = s;
    atomicAdd(&z[dn * HEADS + h], __expf(s));
}

// ---------------------------------------------------------------------------
// Kernel D: a = exp(s)/z[dst] (write to out); rst[dst,h,:] += feat[src,h,:]*a
// one thread per (edge, head); 16 f32 atomics each
// ---------------------------------------------------------------------------
__global__ __launch_bounds__(256) void agg_kernel(
    const int* __restrict__ src, const int* __restrict__ dst,
    const float* __restrict__ s_ws, const float* __restrict__ z,
    const float* __restrict__ feat,
    float* __restrict__ rst, float* __restrict__ a_out)
{
    const int t = blockIdx.x * 256 + threadIdx.x;
    const int e = t >> 2;
    const int h = t & 3;
    if (e >= N_EDGES) return;
    const int sn = src[e], dn = dst[e];
    const float s = s_ws[(size_t)e * HEADS + h];
    const float a = __expf(s) / z[dn * HEADS + h];
    a_out[(size_t)e * HEADS + h] = a;

    const float4* fs = (const float4*)&feat[(size_t)sn * HD + h * OUT_FEATS];
    float* rd = &rst[(size_t)dn * HD + h * OUT_FEATS];
#pragma unroll
    for (int i = 0; i < 4; ++i) {
        float4 f = fs[i];
        atomicAdd(&rd[i * 4 + 0], f.x * a);
        atomicAdd(&rd[i * 4 + 1], f.y * a);
        atomicAdd(&rd[i * 4 + 2], f.z * a);
        atomicAdd(&rd[i * 4 + 3], f.w * a);
    }
}

extern "C" void kernel_launch(void* const* d_in, const int* in_sizes, int n_in,
                              void* d_out, int out_size, void* d_ws, size_t ws_size,
                              hipStream_t stream)
{
    const float* x        = (const float*)d_in[0];
    const float* W        = (const float*)d_in[1];
    const float* W_e      = (const float*)d_in[2];
    const float* attn_l   = (const float*)d_in[3];
    const float* attn_r   = (const float*)d_in[4];
    const float* attn_e   = (const float*)d_in[5];
    const float* edge_emb = (const float*)d_in[6];
    const int* src   = (const int*)d_in[7];
    const int* dst   = (const int*)d_in[8];
    const int* etype = (const int*)d_in[9];

    float* out     = (float*)d_out;
    float* rst_out = out;                              // N*H*D = 6.4M floats
    float* a_out   = out + (size_t)N_NODES * HD;       // E*H   = 6.4M floats

    char* w = (char*)d_ws;
    float* feat = (float*)w;  w += (size_t)N_NODES * HD * 4;       // 25.6 MB
    float* el   = (float*)w;  w += (size_t)N_NODES * HEADS * 4;    //  1.6 MB
    float* er   = (float*)w;  w += (size_t)N_NODES * HEADS * 4;    //  1.6 MB
    float* ee   = (float*)w;  w += 64;
    float* z    = (float*)w;  w += (size_t)N_NODES * HEADS * 4;    //  1.6 MB
    float* s_ws = (float*)w;  w += (size_t)N_EDGES * HEADS * 4;    // 25.6 MB

    // rst accumulates directly in d_out; harness poisons d_out with 0xAA
    // before timed replays, so zero it every call (capturable memset node).
    hipMemsetAsync(rst_out, 0, (size_t)N_NODES * HD * 4, stream);
    hipMemsetAsync(z,       0, (size_t)N_NODES * HEADS * 4, stream);

    feat_el_er_kernel<<<N_NODES / 4, 256, 0, stream>>>(x, W, attn_l, attn_r, feat, el, er);
    ee_kernel<<<N_ETYPES * HEADS, 64, 0, stream>>>(edge_emb, W_e, attn_e, ee);

    const int eh_blocks = (N_EDGES * HEADS) / 256;  // 25000 exactly
    z_kernel<<<eh_blocks, 256, 0, stream>>>(src, dst, etype, el, er, ee, s_ws, z);
    agg_kernel<<<eh_blocks, 256, 0, stream>>>(src, dst, s_ws, z, feat, rst_out, a_out);
}

// Round 3
// 969.766 us; speedup vs baseline: 6.3412x; 6.3412x over previous
//
#include <hip/hip_runtime.h>
#include <hip/hip_bf16.h>

#define N_NODES   100000
#define N_EDGES   1600000
#define N_ETYPES  3
#define IN_FEATS  128
#define HEADS     4
#define OUT_FEATS 16
#define EDGE_FEATS 64
#define HD        64            // HEADS*OUT_FEATS
#define NEG_SLOPE 0.2f
#define ROWS      16            // rows per block in feat kernel

// ---------------------------------------------------------------------------
// Kernel A: feat = x @ W (f32), fused el/er per-node reductions.
// Block = 256 = 4 waves; each wave owns a column set, covers 16 rows (4/thread).
// ---------------------------------------------------------------------------
__global__ __launch_bounds__(256) void feat_el_er_kernel(
    const float* __restrict__ x,
    const float* __restrict__ W,
    const float* __restrict__ attn_l,
    const float* __restrict__ attn_r,
    float* __restrict__ feat,
    float* __restrict__ el,
    float* __restrict__ er)
{
    __shared__ float Wl[IN_FEATS * HD];     // 32 KB
    __shared__ float Xl[ROWS * IN_FEATS];   //  8 KB

    const int t = threadIdx.x;

    {   // W: 8192 f32 = 2048 float4; 8/thread
        const float4* Wg = (const float4*)W;
        float4* Ws = (float4*)Wl;
#pragma unroll
        for (int i = 0; i < 8; ++i) Ws[t + 256 * i] = Wg[t + 256 * i];
    }
    const int row0 = blockIdx.x * ROWS;
    {   // x rows: 2048 f32 = 512 float4; 2/thread
        const float4* Xg = (const float4*)(x + (size_t)row0 * IN_FEATS);
        float4* Xs = (float4*)Xl;
#pragma unroll
        for (int i = 0; i < 2; ++i) Xs[t + 256 * i] = Xg[t + 256 * i];
    }
    __syncthreads();

    const int col = t & 63;        // wave-lane = output col; h*16+d
    const int lr0 = t >> 6;        // 0..3
    const int h   = col >> 4;
    const int d   = col & 15;

    float acc[4] = {0.f, 0.f, 0.f, 0.f};
#pragma unroll 4
    for (int k = 0; k < IN_FEATS; ++k) {
        const float w = Wl[k * HD + col];          // stride-1: conflict-free
#pragma unroll
        for (int r = 0; r < 4; ++r)                // Xl read is wave-uniform: broadcast
            acc[r] += Xl[(lr0 + 4 * r) * IN_FEATS + k] * w;
    }

    const float al = attn_l[h * OUT_FEATS + d];
    const float ar = attn_r[h * OUT_FEATS + d];
#pragma unroll
    for (int r = 0; r < 4; ++r) {
        const int row = row0 + lr0 + 4 * r;
        feat[(size_t)row * HD + col] = acc[r];
        float cl = acc[r] * al;
        float cr = acc[r] * ar;
#pragma unroll
        for (int m = 1; m < 16; m <<= 1) {
            cl += __shfl_xor(cl, m, 64);
            cr += __shfl_xor(cr, m, 64);
        }
        if (d == 0) {
            el[row * HEADS + h] = cl;
            er[row * HEADS + h] = cr;
        }
    }
}

// ---------------------------------------------------------------------------
// Kernel B: ee[t,h] (12 scalars)
// ---------------------------------------------------------------------------
__global__ __launch_bounds__(64) void ee_kernel(
    const float* __restrict__ edge_emb,
    const float* __restrict__ W_e,
    const float* __restrict__ attn_e,
    float* __restrict__ ee)
{
    const int b  = blockIdx.x;     // 0..11
    const int ty = b >> 2;
    const int h  = b & 3;
    const int e  = threadIdx.x;    // 0..63

    float ef = 0.f;
#pragma unroll
    for (int k = 0; k < EDGE_FEATS; ++k)
        ef += edge_emb[ty * EDGE_FEATS + k] *
              W_e[k * (HEADS * EDGE_FEATS) + h * EDGE_FEATS + e];
    float v = ef * attn_e[h * EDGE_FEATS + e];
#pragma unroll
    for (int m = 1; m < 64; m <<= 1) v += __shfl_xor(v, m, 64);
    if (e == 0) ee[ty * HEADS + h] = v;
}

// ---------------------------------------------------------------------------
// CSR build: histogram -> exclusive scan -> scatter
// ---------------------------------------------------------------------------
__global__ __launch_bounds__(256) void hist_kernel(
    const int* __restrict__ dst, int* __restrict__ deg)
{
    const int e = blockIdx.x * 256 + threadIdx.x;
    if (e < N_EDGES) atomicAdd(&deg[dst[e]], 1);
}

// single block, 1024 threads; writes ptr[0..N] and cur[0..N-1]=ptr
__global__ __launch_bounds__(1024) void scan_kernel(
    const int* __restrict__ deg, int* __restrict__ ptr, int* __restrict__ cur)
{
    __shared__ int wsum[16];
    const int t = threadIdx.x;
    const int CH = (N_NODES + 1023) / 1024;   // 98
    const int base = t * CH;

    int sum = 0;
    for (int i = 0; i < CH; ++i) {
        const int idx = base + i;
        if (idx < N_NODES) sum += deg[idx];
    }
    // inclusive scan of per-thread sums
    const int lane = t & 63, wid = t >> 6;
    int v = sum;
#pragma unroll
    for (int m = 1; m < 64; m <<= 1) {
        int u = __shfl_up(v, m, 64);
        if (lane >= m) v += u;
    }
    if (lane == 63) wsum[wid] = v;
    __syncthreads();
    if (wid == 0) {
        int w = (lane < 16) ? wsum[lane] : 0;
#pragma unroll
        for (int m = 1; m < 16; m <<= 1) {
            int u = __shfl_up(w, m, 64);
            if (lane >= m) w += u;
        }
        if (lane < 16) wsum[lane] = w;
    }
    __syncthreads();

    int run = (v - sum) + (wid > 0 ? wsum[wid - 1] : 0);  // exclusive prefix
    for (int i = 0; i < CH; ++i) {
        const int idx = base + i;
        if (idx < N_NODES) {
            ptr[idx] = run;
            cur[idx] = run;
            run += deg[idx];
        }
    }
    if (t == 1023) ptr[N_NODES] = run;   // == N_EDGES
}

__global__ __launch_bounds__(256) void scatter_kernel(
    const int* __restrict__ dst, int* __restrict__ cur, int* __restrict__ eidx)
{
    const int e = blockIdx.x * 256 + threadIdx.x;
    if (e >= N_EDGES) return;
    const int p = atomicAdd(&cur[dst[e]], 1);
    eidx[p] = e;
}

// ---------------------------------------------------------------------------
// Kernel C: per-dst-node aggregation. One 64-lane wave per node; lane = col.
// Pass A: z per head (shuffle-reduced). Pass B: a + rst accumulate, no atomics.
// ---------------------------------------------------------------------------
__global__ __launch_bounds__(256) void agg_kernel(
    const int* __restrict__ src, const int* __restrict__ etype,
    const int* __restrict__ ptr, const int* __restrict__ eidx,
    const float* __restrict__ el, const float* __restrict__ er,
    const float* __restrict__ ee, const float* __restrict__ feat,
    float* __restrict__ rst, float* __restrict__ a_out)
{
    const int wid  = threadIdx.x >> 6;                 // wave in block (0..3)
    const int lane = threadIdx.x & 63;
    const int n    = blockIdx.x * 4 + wid;             // dst node
    if (n >= N_NODES) return;

    const int p0  = ptr[n];
    const int deg = ptr[n + 1] - p0;

    // ---- pass A: z[h] ----
    // lane layout: eo = lane>>2 (0..15), hA = lane&3
    const int hA = lane & 3;
    const float er_nA = er[n * HEADS + hA];
    float zacc = 0.f;
    for (int base = 0; base < deg; base += 16) {
        const int idx = base + (lane >> 2);
        if (idx < deg) {
            const int e  = eidx[p0 + idx];
            const int sn = src[e];
            const int ty = etype[e];
            float s = el[sn * HEADS + hA] + er_nA + ee[ty * HEADS + hA];
            s = s > 0.f ? s : NEG_SLOPE * s;
            zacc += __expf(s);
        }
    }
#pragma unroll
    for (int m = 4; m < 64; m <<= 1) zacc += __shfl_xor(zacc, m, 64);
    // lane c needs z for h=c>>4; lane (c>>4) holds h = (c>>4)&3 = c>>4
    const int h = lane >> 4;
    const float z_me = __shfl(zacc, h, 64);
    const float inv_z = (deg > 0) ? __frcp_rn(z_me) : 0.f;

    // ---- pass B: a + rst ----
    const float er_n = er[n * HEADS + h];
    float racc = 0.f;
    for (int i = 0; i < deg; ++i) {
        const int e  = eidx[p0 + i];     // wave-uniform -> broadcast
        const int sn = src[e];
        const int ty = etype[e];
        float s = el[sn * HEADS + h] + er_n + ee[ty * HEADS + h];
        s = s > 0.f ? s : NEG_SLOPE * s;
        const float a = __expf(s) * inv_z;
        racc += feat[(size_t)sn * HD + lane] * a;
        if ((lane & 15) == 0) a_out[(size_t)e * HEADS + h] = a;
    }
    rst[(size_t)n * HD + lane] = racc;
}

extern "C" void kernel_launch(void* const* d_in, const int* in_sizes, int n_in,
                              void* d_out, int out_size, void* d_ws, size_t ws_size,
                              hipStream_t stream)
{
    const float* x        = (const float*)d_in[0];
    const float* W        = (const float*)d_in[1];
    const float* W_e      = (const float*)d_in[2];
    const float* attn_l   = (const float*)d_in[3];
    const float* attn_r   = (const float*)d_in[4];
    const float* attn_e   = (const float*)d_in[5];
    const float* edge_emb = (const float*)d_in[6];
    const int* src   = (const int*)d_in[7];
    const int* dst   = (const int*)d_in[8];
    const int* etype = (const int*)d_in[9];

    float* out     = (float*)d_out;
    float* rst_out = out;                              // N*H*D
    float* a_out   = out + (size_t)N_NODES * HD;       // E*H

    char* w = (char*)d_ws;
    float* feat = (float*)w;  w += (size_t)N_NODES * HD * 4;       // 25.6 MB
    float* el   = (float*)w;  w += (size_t)N_NODES * HEADS * 4;    //  1.6 MB
    float* er   = (float*)w;  w += (size_t)N_NODES * HEADS * 4;    //  1.6 MB
    float* ee   = (float*)w;  w += 64;
    int*   deg  = (int*)w;    w += (size_t)N_NODES * 4;            //  0.4 MB
    int*   ptr  = (int*)w;    w += (size_t)(N_NODES + 4) * 4;      //  0.4 MB
    int*   cur  = (int*)w;    w += (size_t)N_NODES * 4;            //  0.4 MB
    int*   eidx = (int*)w;    w += (size_t)N_EDGES * 4;            //  6.4 MB

    hipMemsetAsync(deg, 0, (size_t)N_NODES * 4, stream);

    feat_el_er_kernel<<<N_NODES / ROWS, 256, 0, stream>>>(x, W, attn_l, attn_r, feat, el, er);
    ee_kernel<<<N_ETYPES * HEADS, 64, 0, stream>>>(edge_emb, W_e, attn_e, ee);

    hist_kernel<<<N_EDGES / 256, 256, 0, stream>>>(dst, deg);
    scan_kernel<<<1, 1024, 0, stream>>>(deg, ptr, cur);
    scatter_kernel<<<N_EDGES / 256, 256, 0, stream>>>(dst, cur, eidx);

    agg_kernel<<<(N_NODES + 3) / 4, 256, 0, stream>>>(
        src, etype, ptr, eidx, el, er, ee, feat, rst_out, a_out);
}

// Round 4
// 421.982 us; speedup vs baseline: 14.5729x; 2.2981x over previous
//
#include <hip/hip_runtime.h>
#include <hip/hip_bf16.h>

#define N_NODES   100000
#define N_EDGES   1600000
#define N_ETYPES  3
#define IN_FEATS  128
#define HEADS     4
#define OUT_FEATS 16
#define EDGE_FEATS 64
#define HD        64            // HEADS*OUT_FEATS
#define NEG_SLOPE 0.2f
#define ROWS      16            // rows per block in feat kernel
#define NBLK      391           // ceil(N_NODES/256) for scan
#define MAXD_LDS  128           // fast-path max degree (Poisson(16): P(>128)~0)

// ---------------------------------------------------------------------------
// Kernel A: feat = x @ W (f32 accum, bf16 store), fused el/er reductions,
// fused degree-histogram + per-edge rank (grid matches: 6250*256 = N_EDGES).
// The GEMM compute hides the atomic stream's latency/throughput.
// ---------------------------------------------------------------------------
__global__ __launch_bounds__(256) void feat_el_er_hist_kernel(
    const float* __restrict__ x,
    const float* __restrict__ W,
    const float* __restrict__ attn_l,
    const float* __restrict__ attn_r,
    const int*   __restrict__ dst,
    __hip_bfloat16* __restrict__ featb,
    float* __restrict__ el,
    float* __restrict__ er,
    int* __restrict__ deg,
    int* __restrict__ rank)
{
    __shared__ float Wl[IN_FEATS * HD];     // 32 KB
    __shared__ float Xl[ROWS * IN_FEATS];   //  8 KB

    const int t = threadIdx.x;

    // --- fused histogram + rank (one edge per thread) ---
    const int e  = blockIdx.x * 256 + t;
    const int dn = dst[e];
    const int rk = atomicAdd(&deg[dn], 1);

    {   // W: 8192 f32 = 2048 float4; 8/thread
        const float4* Wg = (const float4*)W;
        float4* Ws = (float4*)Wl;
#pragma unroll
        for (int i = 0; i < 8; ++i) Ws[t + 256 * i] = Wg[t + 256 * i];
    }
    const int row0 = blockIdx.x * ROWS;
    {   // x rows: 2048 f32 = 512 float4; 2/thread
        const float4* Xg = (const float4*)(x + (size_t)row0 * IN_FEATS);
        float4* Xs = (float4*)Xl;
#pragma unroll
        for (int i = 0; i < 2; ++i) Xs[t + 256 * i] = Xg[t + 256 * i];
    }
    __syncthreads();

    const int col = t & 63;        // wave-lane = output col; h*16+d
    const int lr0 = t >> 6;        // 0..3
    const int h   = col >> 4;
    const int d   = col & 15;

    float acc[4] = {0.f, 0.f, 0.f, 0.f};
#pragma unroll 4
    for (int k = 0; k < IN_FEATS; ++k) {
        const float w = Wl[k * HD + col];          // stride-1: conflict-free
#pragma unroll
        for (int r = 0; r < 4; ++r)                // Xl read is wave-uniform
            acc[r] += Xl[(lr0 + 4 * r) * IN_FEATS + k] * w;
    }

    rank[e] = rk;   // store after compute so the atomic had time to complete

    const float al = attn_l[h * OUT_FEATS + d];
    const float ar = attn_r[h * OUT_FEATS + d];
#pragma unroll
    for (int r = 0; r < 4; ++r) {
        const int row = row0 + lr0 + 4 * r;
        featb[(size_t)row * HD + col] = __float2bfloat16(acc[r]);
        float cl = acc[r] * al;
        float cr = acc[r] * ar;
#pragma unroll
        for (int m = 1; m < 16; m <<= 1) {
            cl += __shfl_xor(cl, m, 64);
            cr += __shfl_xor(cr, m, 64);
        }
        if (d == 0) {
            el[row * HEADS + h] = cl;
            er[row * HEADS + h] = cr;
        }
    }
}

// ---------------------------------------------------------------------------
// Kernel B: ee[t,h] (12 scalars)
// ---------------------------------------------------------------------------
__global__ __launch_bounds__(64) void ee_kernel(
    const float* __restrict__ edge_emb,
    const float* __restrict__ W_e,
    const float* __restrict__ attn_e,
    float* __restrict__ ee)
{
    const int b  = blockIdx.x;     // 0..11
    const int ty = b >> 2;
    const int h  = b & 3;
    const int e  = threadIdx.x;    // 0..63

    float ef = 0.f;
#pragma unroll
    for (int k = 0; k < EDGE_FEATS; ++k)
        ef += edge_emb[ty * EDGE_FEATS + k] *
              W_e[k * (HEADS * EDGE_FEATS) + h * EDGE_FEATS + e];
    float v = ef * attn_e[h * EDGE_FEATS + e];
#pragma unroll
    for (int m = 1; m < 64; m <<= 1) v += __shfl_xor(v, m, 64);
    if (e == 0) ee[ty * HEADS + h] = v;
}

// ---------------------------------------------------------------------------
// Multiblock exclusive scan of deg -> ptr  (3 tiny kernels)
// ---------------------------------------------------------------------------
__device__ __forceinline__ int wave_incl_scan(int v, int lane) {
#pragma unroll
    for (int m = 1; m < 64; m <<= 1) {
        int u = __shfl_up(v, m, 64);
        if (lane >= m) v += u;
    }
    return v;
}

__global__ __launch_bounds__(256) void scan_a_kernel(
    const int* __restrict__ deg, int* __restrict__ ptr, int* __restrict__ bsum)
{
    __shared__ int ws[4];
    const int t = threadIdx.x, lane = t & 63, wid = t >> 6;
    const int i = blockIdx.x * 256 + t;
    const int v = (i < N_NODES) ? deg[i] : 0;
    const int inc = wave_incl_scan(v, lane);
    if (lane == 63) ws[wid] = inc;
    __syncthreads();
    int woff = 0;
    for (int k = 0; k < wid; ++k) woff += ws[k];
    const int excl = inc - v + woff;
    if (i < N_NODES) ptr[i] = excl;
    if (t == 255) bsum[blockIdx.x] = excl + v;   // block total
}

__global__ __launch_bounds__(512) void scan_b_kernel(
    int* __restrict__ bsum, int* __restrict__ ptr)
{
    __shared__ int ws[8];
    const int t = threadIdx.x, lane = t & 63, wid = t >> 6;
    const int v = (t < NBLK) ? bsum[t] : 0;
    const int inc = wave_incl_scan(v, lane);
    if (lane == 63) ws[wid] = inc;
    __syncthreads();
    int woff = 0;
    for (int k = 0; k < wid; ++k) woff += ws[k];
    if (t < NBLK) bsum[t] = inc - v + woff;      // exclusive block offsets
    if (t == 0) ptr[N_NODES] = N_EDGES;
}

__global__ __launch_bounds__(256) void scan_c_kernel(
    int* __restrict__ ptr, const int* __restrict__ bsum)
{
    const int i = blockIdx.x * 256 + threadIdx.x;
    if (i < N_NODES) ptr[i] += bsum[blockIdx.x];
}

// ---------------------------------------------------------------------------
// Atomic-free scatter: sc_csr[ptr[dst]+rank] = {src, e | etype<<24}
// ---------------------------------------------------------------------------
__global__ __launch_bounds__(256) void scatter_kernel(
    const int* __restrict__ src, const int* __restrict__ dst,
    const int* __restrict__ etype, const int* __restrict__ rank,
    const int* __restrict__ ptr, int2* __restrict__ sc_csr)
{
    const int e = blockIdx.x * 256 + threadIdx.x;   // grid covers exactly N_EDGES
    const int dn = dst[e];
    const int p  = ptr[dn] + rank[e];
    sc_csr[p] = make_int2(src[e], e | (etype[e] << 24));
}

// ---------------------------------------------------------------------------
// Kernel C: per-dst-node aggregation. One wave per node; lane = col (h*16+d).
// Pass A: w=exp(s) once per (edge,head) -> LDS; z by shuffle-reduce.
// Pass B: a = w*inv_z from LDS; bf16 feat gather; no atomics anywhere.
// ---------------------------------------------------------------------------
__global__ __launch_bounds__(256) void agg_kernel(
    const int2* __restrict__ sc_csr, const int* __restrict__ ptr,
    const float* __restrict__ el, const float* __restrict__ er,
    const float* __restrict__ ee, const __hip_bfloat16* __restrict__ featb,
    float* __restrict__ rst, float* __restrict__ a_out)
{
    __shared__ float w_lds[4][MAXD_LDS * HEADS];   // 8 KB
    const int wid  = threadIdx.x >> 6;
    const int lane = threadIdx.x & 63;
    const int n    = blockIdx.x * 4 + wid;         // 25000*4 = N_NODES exact

    const int p0  = ptr[n];
    const int deg = ptr[n + 1] - p0;
    float* wl = w_lds[wid];

    // ---- pass A: lane = (eo = lane>>2, hA = lane&3) ----
    const int hA = lane & 3;
    const int eo = lane >> 2;
    const float er_nA = er[n * HEADS + hA];
    const float ee0 = ee[0 * HEADS + hA];
    const float ee1 = ee[1 * HEADS + hA];
    const float ee2 = ee[2 * HEADS + hA];
    float zacc = 0.f;
    const bool fast = (deg <= MAXD_LDS);
    for (int base = 0; base < deg; base += 16) {
        const int idx = base + eo;
        if (idx < deg) {
            const int2 sc = sc_csr[p0 + idx];
            const int sn = sc.x;
            const int ty = sc.y >> 24;
            const float eeh = (ty == 0) ? ee0 : ((ty == 1) ? ee1 : ee2);
            float s = el[sn * HEADS + hA] + er_nA + eeh;
            s = s > 0.f ? s : NEG_SLOPE * s;
            const float wv = __expf(s);
            if (fast) wl[idx * HEADS + hA] = wv;   // banks 0..63 pattern: conflict-free
            zacc += wv;
        }
    }
#pragma unroll
    for (int m = 4; m < 64; m <<= 1) zacc += __shfl_xor(zacc, m, 64);
    const int h = lane >> 4;
    const int d = lane & 15;
    const float z_me  = __shfl(zacc, h, 64);       // lane h holds z for head h
    const float inv_z = (deg > 0) ? __frcp_rn(z_me) : 0.f;

    // ---- pass B ----
    float racc = 0.f;
    if (fast) {
        for (int i = 0; i < deg; ++i) {
            const int2 sc = sc_csr[p0 + i];        // wave-uniform, L1-hot
            const int sn = sc.x;
            const float a = wl[i * HEADS + h] * inv_z;   // LDS broadcast
            racc += __bfloat162float(featb[(size_t)sn * HD + lane]) * a;
            if (d == 0) a_out[(size_t)(sc.y & 0xFFFFFF) * HEADS + h] = a;
        }
    } else {   // astronomically rare: recompute per edge
        const float er_n = er[n * HEADS + h];
        const float f0 = ee[h], f1 = ee[HEADS + h], f2 = ee[2 * HEADS + h];
        for (int i = 0; i < deg; ++i) {
            const int2 sc = sc_csr[p0 + i];
            const int sn = sc.x;
            const int ty = sc.y >> 24;
            const float eeh = (ty == 0) ? f0 : ((ty == 1) ? f1 : f2);
            float s = el[sn * HEADS + h] + er_n + eeh;
            s = s > 0.f ? s : NEG_SLOPE * s;
            const float a = __expf(s) * inv_z;
            racc += __bfloat162float(featb[(size_t)sn * HD + lane]) * a;
            if (d == 0) a_out[(size_t)(sc.y & 0xFFFFFF) * HEADS + h] = a;
        }
    }
    rst[(size_t)n * HD + lane] = racc;
}

extern "C" void kernel_launch(void* const* d_in, const int* in_sizes, int n_in,
                              void* d_out, int out_size, void* d_ws, size_t ws_size,
                              hipStream_t stream)
{
    const float* x        = (const float*)d_in[0];
    const float* W        = (const float*)d_in[1];
    const float* W_e      = (const float*)d_in[2];
    const float* attn_l   = (const float*)d_in[3];
    const float* attn_r   = (const float*)d_in[4];
    const float* attn_e   = (const float*)d_in[5];
    const float* edge_emb = (const float*)d_in[6];
    const int* src   = (const int*)d_in[7];
    const int* dst   = (const int*)d_in[8];
    const int* etype = (const int*)d_in[9];

    float* out     = (float*)d_out;
    float* rst_out = out;                              // N*H*D
    float* a_out   = out + (size_t)N_NODES * HD;       // E*H

    char* w = (char*)d_ws;
    __hip_bfloat16* featb = (__hip_bfloat16*)w; w += (size_t)N_NODES * HD * 2;  // 12.8 MB
    float* el   = (float*)w;  w += (size_t)N_NODES * HEADS * 4;    //  1.6 MB
    float* er   = (float*)w;  w += (size_t)N_NODES * HEADS * 4;    //  1.6 MB
    float* ee   = (float*)w;  w += 64;
    int*   deg  = (int*)w;    w += (size_t)N_NODES * 4;            //  0.4 MB
    int*   ptr  = (int*)w;    w += (size_t)(N_NODES + 4) * 4;      //  0.4 MB
    int*   rank = (int*)w;    w += (size_t)N_EDGES * 4;            //  6.4 MB
    int*   bsum = (int*)w;    w += (size_t)512 * 4;
    int2*  sc   = (int2*)w;   w += (size_t)N_EDGES * 8;            // 12.8 MB

    hipMemsetAsync(deg, 0, (size_t)N_NODES * 4, stream);

    feat_el_er_hist_kernel<<<N_NODES / ROWS, 256, 0, stream>>>(
        x, W, attn_l, attn_r, dst, featb, el, er, deg, rank);
    ee_kernel<<<N_ETYPES * HEADS, 64, 0, stream>>>(edge_emb, W_e, attn_e, ee);

    scan_a_kernel<<<NBLK, 256, 0, stream>>>(deg, ptr, bsum);
    scan_b_kernel<<<1, 512, 0, stream>>>(bsum, ptr);
    scan_c_kernel<<<NBLK, 256, 0, stream>>>(ptr, bsum);

    scatter_kernel<<<N_EDGES / 256, 256, 0, stream>>>(src, dst, etype, rank, ptr, sc);

    agg_kernel<<<N_NODES / 4, 256, 0, stream>>>(
        sc, ptr, el, er, ee, featb, rst_out, a_out);
}

// Round 5
// 340.175 us; speedup vs baseline: 18.0774x; 1.2405x over previous
//
#include <hip/hip_runtime.h>
#include <hip/hip_bf16.h>

#define N_NODES   100000
#define N_EDGES   1600000
#define N_ETYPES  3
#define IN_FEATS  128
#define HEADS     4
#define OUT_FEATS 16
#define EDGE_FEATS 64
#define HD        64            // HEADS*OUT_FEATS
#define NEG_SLOPE 0.2f
#define NBLK      391           // ceil(N_NODES/256) for scan
#define MAXD_LDS  128           // fast-path max degree

typedef short s16x8 __attribute__((ext_vector_type(8)));
typedef float f32x4 __attribute__((ext_vector_type(4)));

__device__ __forceinline__ short f2bs(float f) {
    __hip_bfloat16 h = __float2bfloat16(f);
    return *reinterpret_cast<short*>(&h);
}

// ---------------------------------------------------------------------------
// Prep: WT bf16 [64][128]  (WT[n][k] = W[k][n])
// ---------------------------------------------------------------------------
__global__ __launch_bounds__(256) void wt_prep_kernel(
    const float* __restrict__ W, short* __restrict__ WTb)
{
    const int t = blockIdx.x * 256 + threadIdx.x;   // 0..8191
    const int k = t >> 6, n = t & 63;
    WTb[n * IN_FEATS + k] = f2bs(W[t]);
}

// ---------------------------------------------------------------------------
// Kernel A (MFMA): feat = x @ W, bf16 store, fused el/er + degree-hist + rank.
// Block: 256 thr = 4 waves; wave w = head w (cols 16w..16w+15); M-tile = 16.
// Grid 6250 matches edges exactly (6250*256 = N_EDGES).
// A-frag: A[m=lane&15][k=quad*8+j]; B-frag: B[k=quad*8+j][n=lane&15];
// C/D: col=lane&15, row=quad*4+reg  (learn_hip m89/m91 verified mappings).
// ---------------------------------------------------------------------------
#define XS_STRIDE 136   // 128 + 8 pad shorts: 272 B rows, 16B-aligned, 2-way banks
__global__ __launch_bounds__(256) void feat_el_er_hist_kernel(
    const float* __restrict__ x,
    const short* __restrict__ WTb,
    const float* __restrict__ attn_l,
    const float* __restrict__ attn_r,
    const int*   __restrict__ dst,
    __hip_bfloat16* __restrict__ featb,
    float* __restrict__ el,
    float* __restrict__ er,
    int* __restrict__ deg,
    int* __restrict__ rank)
{
    __shared__ short Xs[16 * XS_STRIDE];   //  4.3 KB
    __shared__ short Ws[64 * XS_STRIDE];   // 17.4 KB

    const int t = threadIdx.x;

    // fused histogram + rank
    const int e  = blockIdx.x * 256 + t;
    const int dn = dst[e];
    const int rk = atomicAdd(&deg[dn], 1);

    const int row0 = blockIdx.x * 16;
    {   // stage x -> bf16 LDS: thread: row = t>>4, k0 = (t&15)*8
        const int r = t >> 4, k0 = (t & 15) * 8;
        const float4* xg = (const float4*)(x + (size_t)(row0 + r) * IN_FEATS + k0);
        const float4 v0 = xg[0], v1 = xg[1];
        s16x8 p;
        p[0] = f2bs(v0.x); p[1] = f2bs(v0.y); p[2] = f2bs(v0.z); p[3] = f2bs(v0.w);
        p[4] = f2bs(v1.x); p[5] = f2bs(v1.y); p[6] = f2bs(v1.z); p[7] = f2bs(v1.w);
        *(s16x8*)&Xs[r * XS_STRIDE + k0] = p;
    }
    {   // stage WT bf16: 8192 shorts, 4 x s16x8 per thread
#pragma unroll
        for (int j = 0; j < 4; ++j) {
            const int u = t + 256 * j;          // unit = 8 shorts
            const int r = u >> 4, c = (u & 15) * 8;
            *(s16x8*)&Ws[r * XS_STRIDE + c] = *(const s16x8*)(WTb + r * IN_FEATS + c);
        }
    }
    __syncthreads();

    const int w    = t >> 6;        // wave = head
    const int lane = t & 63;
    const int m    = lane & 15;     // A-row m / B-col n / C-col
    const int q    = lane >> 4;     // quad

    f32x4 acc = {0.f, 0.f, 0.f, 0.f};
#pragma unroll
    for (int kb = 0; kb < 4; ++kb) {
        const s16x8 af = *(const s16x8*)&Xs[m * XS_STRIDE + kb * 32 + q * 8];
        const s16x8 bf = *(const s16x8*)&Ws[(w * 16 + m) * XS_STRIDE + kb * 32 + q * 8];
        acc = __builtin_amdgcn_mfma_f32_16x16x32_bf16(af, bf, acc, 0, 0, 0);
    }

    rank[e] = rk;   // after compute: atomic return latency hidden

    const float al = attn_l[w * OUT_FEATS + m];
    const float ar = attn_r[w * OUT_FEATS + m];
#pragma unroll
    for (int r = 0; r < 4; ++r) {
        const int row = row0 + q * 4 + r;
        featb[(size_t)row * HD + w * 16 + m] = __float2bfloat16(acc[r]);
        float cl = acc[r] * al;
        float cr = acc[r] * ar;
#pragma unroll
        for (int msk = 1; msk < 16; msk <<= 1) {
            cl += __shfl_xor(cl, msk, 64);
            cr += __shfl_xor(cr, msk, 64);
        }
        if (m == 0) {
            el[row * HEADS + w] = cl;
            er[row * HEADS + w] = cr;
        }
    }
}

// ---------------------------------------------------------------------------
// Kernel B: ee[t,h] (12 scalars)
// ---------------------------------------------------------------------------
__global__ __launch_bounds__(64) void ee_kernel(
    const float* __restrict__ edge_emb,
    const float* __restrict__ W_e,
    const float* __restrict__ attn_e,
    float* __restrict__ ee)
{
    const int b  = blockIdx.x;     // 0..11
    const int ty = b >> 2;
    const int h  = b & 3;
    const int e  = threadIdx.x;    // 0..63

    float ef = 0.f;
#pragma unroll
    for (int k = 0; k < EDGE_FEATS; ++k)
        ef += edge_emb[ty * EDGE_FEATS + k] *
              W_e[k * (HEADS * EDGE_FEATS) + h * EDGE_FEATS + e];
    float v = ef * attn_e[h * EDGE_FEATS + e];
#pragma unroll
    for (int m = 1; m < 64; m <<= 1) v += __shfl_xor(v, m, 64);
    if (e == 0) ee[ty * HEADS + h] = v;
}

// ---------------------------------------------------------------------------
// Multiblock exclusive scan of deg -> ptr
// ---------------------------------------------------------------------------
__device__ __forceinline__ int wave_incl_scan(int v, int lane) {
#pragma unroll
    for (int m = 1; m < 64; m <<= 1) {
        int u = __shfl_up(v, m, 64);
        if (lane >= m) v += u;
    }
    return v;
}

__global__ __launch_bounds__(256) void scan_a_kernel(
    const int* __restrict__ deg, int* __restrict__ ptr, int* __restrict__ bsum)
{
    __shared__ int ws[4];
    const int t = threadIdx.x, lane = t & 63, wid = t >> 6;
    const int i = blockIdx.x * 256 + t;
    const int v = (i < N_NODES) ? deg[i] : 0;
    const int inc = wave_incl_scan(v, lane);
    if (lane == 63) ws[wid] = inc;
    __syncthreads();
    int woff = 0;
    for (int k = 0; k < wid; ++k) woff += ws[k];
    const int excl = inc - v + woff;
    if (i < N_NODES) ptr[i] = excl;
    if (t == 255) bsum[blockIdx.x] = excl + v;
}

__global__ __launch_bounds__(512) void scan_b_kernel(
    int* __restrict__ bsum, int* __restrict__ ptr)
{
    __shared__ int ws[8];
    const int t = threadIdx.x, lane = t & 63, wid = t >> 6;
    const int v = (t < NBLK) ? bsum[t] : 0;
    const int inc = wave_incl_scan(v, lane);
    if (lane == 63) ws[wid] = inc;
    __syncthreads();
    int woff = 0;
    for (int k = 0; k < wid; ++k) woff += ws[k];
    if (t < NBLK) bsum[t] = inc - v + woff;
    if (t == 0) ptr[N_NODES] = N_EDGES;
}

__global__ __launch_bounds__(256) void scan_c_kernel(
    int* __restrict__ ptr, const int* __restrict__ bsum)
{
    const int i = blockIdx.x * 256 + threadIdx.x;
    if (i < N_NODES) ptr[i] += bsum[blockIdx.x];
}

// ---------------------------------------------------------------------------
// Atomic-free scatter: sc_csr[ptr[dst]+rank] = {src, e | etype<<24}
// ---------------------------------------------------------------------------
__global__ __launch_bounds__(256) void scatter_kernel(
    const int* __restrict__ src, const int* __restrict__ dst,
    const int* __restrict__ etype, const int* __restrict__ rank,
    const int* __restrict__ ptr, int2* __restrict__ sc_csr)
{
    const int e = blockIdx.x * 256 + threadIdx.x;
    const int dn = dst[e];
    const int p  = ptr[dn] + rank[e];
    sc_csr[p] = make_int2(src[e], e | (etype[e] << 24));
}

// ---------------------------------------------------------------------------
// Kernel C: per-dst aggregation, one wave per node.
// Pass A: w=exp(s) -> LDS (lane = (eo,hA)); z shuffle-reduced.
// Pass B: half-wave per edge, ushort2 per lane (2 cols), 4 edges in flight.
// ---------------------------------------------------------------------------
__global__ __launch_bounds__(256) void agg_kernel(
    const int2* __restrict__ sc_csr, const int* __restrict__ ptr,
    const float* __restrict__ el, const float* __restrict__ er,
    const float* __restrict__ ee, const __hip_bfloat16* __restrict__ featb,
    float* __restrict__ rst, float* __restrict__ a_out)
{
    __shared__ float w_lds[4][MAXD_LDS * HEADS];   // 8 KB
    const int wid  = threadIdx.x >> 6;
    const int lane = threadIdx.x & 63;
    const int n    = blockIdx.x * 4 + wid;

    const int p0  = ptr[n];
    const int deg = ptr[n + 1] - p0;
    float* wl = w_lds[wid];

    // ---- pass A ----
    const int hA = lane & 3;
    const int eo = lane >> 2;
    const float er_nA = er[n * HEADS + hA];
    const float ee0 = ee[0 * HEADS + hA];
    const float ee1 = ee[1 * HEADS + hA];
    const float ee2 = ee[2 * HEADS + hA];
    float zacc = 0.f;
    const bool fast = (deg <= MAXD_LDS);
    for (int base = 0; base < deg; base += 16) {
        const int idx = base + eo;
        if (idx < deg) {
            const int2 sc = sc_csr[p0 + idx];
            const int ty = sc.y >> 24;
            const float eeh = (ty == 0) ? ee0 : ((ty == 1) ? ee1 : ee2);
            float s = el[sc.x * HEADS + hA] + er_nA + eeh;
            s = s > 0.f ? s : NEG_SLOPE * s;
            const float wv = __expf(s);
            if (fast) wl[idx * HEADS + hA] = wv;
            zacc += wv;
        }
    }
#pragma unroll
    for (int m = 4; m < 64; m <<= 1) zacc += __shfl_xor(zacc, m, 64);
    // after reduction every lane holds z for head (lane&3)

    // ---- pass B ----
    if (fast) {
        const int half  = lane >> 5;          // 0/1: which edge of the pair
        const int cpair = lane & 31;          // cols 2*cpair, 2*cpair+1
        const int hB    = cpair >> 3;         // head of both cols
        const float inv_z = (deg > 0) ? __frcp_rn(__shfl(zacc, hB, 64)) : 0.f;
        float rx = 0.f, ry = 0.f;
        int i = 0;
        for (; i + 4 <= deg; i += 4) {
            const int2 sc0 = sc_csr[p0 + i + half];
            const int2 sc1 = sc_csr[p0 + i + 2 + half];
            const uint f0 = *(const uint*)((const ushort*)featb + ((size_t)sc0.x << 6) + (cpair << 1));
            const uint f1 = *(const uint*)((const ushort*)featb + ((size_t)sc1.x << 6) + (cpair << 1));
            const float a0 = wl[(i + half) * HEADS + hB] * inv_z;
            const float a1 = wl[(i + 2 + half) * HEADS + hB] * inv_z;
            rx += __uint_as_float(f0 << 16) * a0;
            ry += __uint_as_float(f0 & 0xFFFF0000u) * a0;
            rx += __uint_as_float(f1 << 16) * a1;
            ry += __uint_as_float(f1 & 0xFFFF0000u) * a1;
            if ((lane & 7) == 0) {
                a_out[(size_t)(sc0.y & 0xFFFFFF) * HEADS + hB] = a0;
                a_out[(size_t)(sc1.y & 0xFFFFFF) * HEADS + hB] = a1;
            }
        }
        if (i + 2 <= deg) {
            const int2 sc0 = sc_csr[p0 + i + half];
            const uint f0 = *(const uint*)((const ushort*)featb + ((size_t)sc0.x << 6) + (cpair << 1));
            const float a0 = wl[(i + half) * HEADS + hB] * inv_z;
            rx += __uint_as_float(f0 << 16) * a0;
            ry += __uint_as_float(f0 & 0xFFFF0000u) * a0;
            if ((lane & 7) == 0)
                a_out[(size_t)(sc0.y & 0xFFFFFF) * HEADS + hB] = a0;
            i += 2;
        }
        if (i < deg) {   // last single edge: half 0 only
            const int2 sc0 = sc_csr[p0 + i];
            const uint f0 = *(const uint*)((const ushort*)featb + ((size_t)sc0.x << 6) + (cpair << 1));
            const float a0 = wl[i * HEADS + hB] * inv_z;
            if (half == 0) {
                rx += __uint_as_float(f0 << 16) * a0;
                ry += __uint_as_float(f0 & 0xFFFF0000u) * a0;
                if ((lane & 7) == 0)
                    a_out[(size_t)(sc0.y & 0xFFFFFF) * HEADS + hB] = a0;
            }
        }
        rx += __shfl_xor(rx, 32, 64);
        ry += __shfl_xor(ry, 32, 64);
        if (half == 0) {
            float2 v = make_float2(rx, ry);
            *(float2*)(rst + (size_t)n * HD + (cpair << 1)) = v;
        }
    } else {   // rare big-degree fallback: lane = col layout, recompute per edge
        const int h = lane >> 4;
        const int d = lane & 15;
        const float inv_z = (deg > 0) ? __frcp_rn(__shfl(zacc, h, 64)) : 0.f;
        const float er_n = er[n * HEADS + h];
        const float g0 = ee[h], g1 = ee[HEADS + h], g2 = ee[2 * HEADS + h];
        float racc = 0.f;
        for (int i = 0; i < deg; ++i) {
            const int2 sc = sc_csr[p0 + i];
            const int ty = sc.y >> 24;
            const float eeh = (ty == 0) ? g0 : ((ty == 1) ? g1 : g2);
            float s = el[sc.x * HEADS + h] + er_n + eeh;
            s = s > 0.f ? s : NEG_SLOPE * s;
            const float a = __expf(s) * inv_z;
            racc += __bfloat162float(featb[(size_t)sc.x * HD + lane]) * a;
            if (d == 0) a_out[(size_t)(sc.y & 0xFFFFFF) * HEADS + h] = a;
        }
        rst[(size_t)n * HD + lane] = racc;
    }
}

extern "C" void kernel_launch(void* const* d_in, const int* in_sizes, int n_in,
                              void* d_out, int out_size, void* d_ws, size_t ws_size,
                              hipStream_t stream)
{
    const float* x        = (const float*)d_in[0];
    const float* W        = (const float*)d_in[1];
    const float* W_e      = (const float*)d_in[2];
    const float* attn_l   = (const float*)d_in[3];
    const float* attn_r   = (const float*)d_in[4];
    const float* attn_e   = (const float*)d_in[5];
    const float* edge_emb = (const float*)d_in[6];
    const int* src   = (const int*)d_in[7];
    const int* dst   = (const int*)d_in[8];
    const int* etype = (const int*)d_in[9];

    float* out     = (float*)d_out;
    float* rst_out = out;                              // N*H*D
    float* a_out   = out + (size_t)N_NODES * HD;       // E*H

    char* w = (char*)d_ws;
    __hip_bfloat16* featb = (__hip_bfloat16*)w; w += (size_t)N_NODES * HD * 2;  // 12.8 MB
    float* el   = (float*)w;  w += (size_t)N_NODES * HEADS * 4;    //  1.6 MB
    float* er   = (float*)w;  w += (size_t)N_NODES * HEADS * 4;    //  1.6 MB
    float* ee   = (float*)w;  w += 64;
    int*   deg  = (int*)w;    w += (size_t)N_NODES * 4;            //  0.4 MB
    int*   ptr  = (int*)w;    w += (size_t)(N_NODES + 4) * 4;      //  0.4 MB
    int*   rank = (int*)w;    w += (size_t)N_EDGES * 4;            //  6.4 MB
    int*   bsum = (int*)w;    w += (size_t)512 * 4;
    short* WTb  = (short*)w;  w += (size_t)HD * IN_FEATS * 2;      //  16 KB
    int2*  sc   = (int2*)w;   w += (size_t)N_EDGES * 8;            // 12.8 MB

    hipMemsetAsync(deg, 0, (size_t)N_NODES * 4, stream);

    wt_prep_kernel<<<(IN_FEATS * HD) / 256, 256, 0, stream>>>(W, WTb);

    feat_el_er_hist_kernel<<<N_NODES / 16, 256, 0, stream>>>(
        x, WTb, attn_l, attn_r, dst, featb, el, er, deg, rank);
    ee_kernel<<<N_ETYPES * HEADS, 64, 0, stream>>>(edge_emb, W_e, attn_e, ee);

    scan_a_kernel<<<NBLK, 256, 0, stream>>>(deg, ptr, bsum);
    scan_b_kernel<<<1, 512, 0, stream>>>(bsum, ptr);
    scan_c_kernel<<<NBLK, 256, 0, stream>>>(ptr, bsum);

    scatter_kernel<<<N_EDGES / 256, 256, 0, stream>>>(src, dst, etype, rank, ptr, sc);

    agg_kernel<<<N_NODES / 4, 256, 0, stream>>>(
        sc, ptr, el, er, ee, featb, rst_out, a_out);
}

// Round 6
// 304.350 us; speedup vs baseline: 20.2053x; 1.1177x over previous
//
#include <hip/hip_runtime.h>
#include <hip/hip_bf16.h>

#define N_NODES   100000
#define N_EDGES   1600000
#define N_ETYPES  3
#define IN_FEATS  128
#define HEADS     4
#define OUT_FEATS 16
#define EDGE_FEATS 64
#define HD        64            // HEADS*OUT_FEATS
#define NEG_SLOPE 0.2f
#define MAXD_LDS  128           // agg fast-path max degree (Poisson(16): P(>128)~0)

#define NBUCK     400           // buckets for counting sort
#define NPB       250           // nodes per bucket (400*250 = N_NODES)
#define PBLK      400           // blocks in pass1/pass2
#define EPB       4000          // edges per block (400*4000 = N_EDGES)

typedef short s16x8 __attribute__((ext_vector_type(8)));
typedef float f32x4 __attribute__((ext_vector_type(4)));

__device__ __forceinline__ short f2bs(float f) {
    __hip_bfloat16 h = __float2bfloat16(f);
    return *reinterpret_cast<short*>(&h);
}

// ---------------------------------------------------------------------------
// Prep: WT bf16 [64][128]  (WT[n][k] = W[k][n])
// ---------------------------------------------------------------------------
__global__ __launch_bounds__(256) void wt_prep_kernel(
    const float* __restrict__ W, short* __restrict__ WTb)
{
    const int t = blockIdx.x * 256 + threadIdx.x;   // 0..8191
    const int k = t >> 6, n = t & 63;
    WTb[n * IN_FEATS + k] = f2bs(W[t]);
}

// ---------------------------------------------------------------------------
// Kernel A (MFMA): feat = x @ W, bf16 store, fused el/er. Pure GEMM now.
// Block: 256 thr = 4 waves; wave w = head w (cols 16w..16w+15); M-tile = 16.
// ---------------------------------------------------------------------------
#define XS_STRIDE 136   // 128 + 8 pad shorts
__global__ __launch_bounds__(256) void feat_el_er_kernel(
    const float* __restrict__ x,
    const short* __restrict__ WTb,
    const float* __restrict__ attn_l,
    const float* __restrict__ attn_r,
    __hip_bfloat16* __restrict__ featb,
    float* __restrict__ el,
    float* __restrict__ er)
{
    __shared__ short Xs[16 * XS_STRIDE];
    __shared__ short Ws[64 * XS_STRIDE];

    const int t = threadIdx.x;
    const int row0 = blockIdx.x * 16;
    {   // stage x -> bf16 LDS
        const int r = t >> 4, k0 = (t & 15) * 8;
        const float4* xg = (const float4*)(x + (size_t)(row0 + r) * IN_FEATS + k0);
        const float4 v0 = xg[0], v1 = xg[1];
        s16x8 p;
        p[0] = f2bs(v0.x); p[1] = f2bs(v0.y); p[2] = f2bs(v0.z); p[3] = f2bs(v0.w);
        p[4] = f2bs(v1.x); p[5] = f2bs(v1.y); p[6] = f2bs(v1.z); p[7] = f2bs(v1.w);
        *(s16x8*)&Xs[r * XS_STRIDE + k0] = p;
    }
    {   // stage WT bf16
#pragma unroll
        for (int j = 0; j < 4; ++j) {
            const int u = t + 256 * j;
            const int r = u >> 4, c = (u & 15) * 8;
            *(s16x8*)&Ws[r * XS_STRIDE + c] = *(const s16x8*)(WTb + r * IN_FEATS + c);
        }
    }
    __syncthreads();

    const int w    = t >> 6;
    const int lane = t & 63;
    const int m    = lane & 15;
    const int q    = lane >> 4;

    f32x4 acc = {0.f, 0.f, 0.f, 0.f};
#pragma unroll
    for (int kb = 0; kb < 4; ++kb) {
        const s16x8 af = *(const s16x8*)&Xs[m * XS_STRIDE + kb * 32 + q * 8];
        const s16x8 bf = *(const s16x8*)&Ws[(w * 16 + m) * XS_STRIDE + kb * 32 + q * 8];
        acc = __builtin_amdgcn_mfma_f32_16x16x32_bf16(af, bf, acc, 0, 0, 0);
    }

    const float al = attn_l[w * OUT_FEATS + m];
    const float ar = attn_r[w * OUT_FEATS + m];
#pragma unroll
    for (int r = 0; r < 4; ++r) {
        const int row = row0 + q * 4 + r;
        featb[(size_t)row * HD + w * 16 + m] = __float2bfloat16(acc[r]);
        float cl = acc[r] * al;
        float cr = acc[r] * ar;
#pragma unroll
        for (int msk = 1; msk < 16; msk <<= 1) {
            cl += __shfl_xor(cl, msk, 64);
            cr += __shfl_xor(cr, msk, 64);
        }
        if (m == 0) {
            el[row * HEADS + w] = cl;
            er[row * HEADS + w] = cr;
        }
    }
}

// ---------------------------------------------------------------------------
// Kernel B: ee[t,h] (12 scalars)
// ---------------------------------------------------------------------------
__global__ __launch_bounds__(64) void ee_kernel(
    const float* __restrict__ edge_emb,
    const float* __restrict__ W_e,
    const float* __restrict__ attn_e,
    float* __restrict__ ee)
{
    const int b  = blockIdx.x;
    const int ty = b >> 2;
    const int h  = b & 3;
    const int e  = threadIdx.x;

    float ef = 0.f;
#pragma unroll
    for (int k = 0; k < EDGE_FEATS; ++k)
        ef += edge_emb[ty * EDGE_FEATS + k] *
              W_e[k * (HEADS * EDGE_FEATS) + h * EDGE_FEATS + e];
    float v = ef * attn_e[h * EDGE_FEATS + e];
#pragma unroll
    for (int m = 1; m < 64; m <<= 1) v += __shfl_xor(v, m, 64);
    if (e == 0) ee[ty * HEADS + h] = v;
}

// ---------------------------------------------------------------------------
// CSR build via bucketed counting sort — all hot atomics in LDS.
// ---------------------------------------------------------------------------
// Pass 1: per-block LDS histogram over buckets. bhist[blk*NBUCK + bucket].
__global__ __launch_bounds__(256) void bucket_hist_kernel(
    const int* __restrict__ dst, int* __restrict__ bhist)
{
    __shared__ int h[NBUCK];
    const int t = threadIdx.x, b = blockIdx.x;
    for (int j = t; j < NBUCK; j += 256) h[j] = 0;
    __syncthreads();
    const int e0 = b * EPB;
    for (int i = t; i < EPB; i += 256)
        atomicAdd(&h[dst[e0 + i] / NPB], 1);
    __syncthreads();
    for (int j = t; j < NBUCK; j += 256) bhist[b * NBUCK + j] = h[j];
}

// k1: per bucket j, exclusive scan over blocks; btot[j] = total.
__global__ __launch_bounds__(256) void bucket_scan1_kernel(
    int* __restrict__ bhist, int* __restrict__ btot)
{
    __shared__ int sh[PBLK];
    const int t = threadIdx.x, j = blockIdx.x;
    const int j0 = t, j1 = t + 256;
    int o0 = 0, o1 = 0;
    if (j0 < PBLK) { o0 = bhist[j0 * NBUCK + j]; sh[j0] = o0; }
    if (j1 < PBLK) { o1 = bhist[j1 * NBUCK + j]; sh[j1] = o1; }
    __syncthreads();
    for (int off = 1; off < PBLK; off <<= 1) {
        int v0 = (j0 >= off && j0 < PBLK) ? sh[j0 - off] : 0;
        int v1 = (j1 >= off && j1 < PBLK) ? sh[j1 - off] : 0;
        __syncthreads();
        if (j0 < PBLK) sh[j0] += v0;
        if (j1 < PBLK) sh[j1] += v1;
        __syncthreads();
    }
    if (j0 < PBLK) bhist[j0 * NBUCK + j] = sh[j0] - o0;
    if (j1 < PBLK) bhist[j1 * NBUCK + j] = sh[j1] - o1;
    if (t == 255) btot[j] = sh[PBLK - 1];
}

// k2: single block: exclusive scan btot[NBUCK] -> bbase[NBUCK+1]
__global__ __launch_bounds__(512) void bucket_scan2_kernel(
    const int* __restrict__ btot, int* __restrict__ bbase)
{
    __shared__ int sh[NBUCK];
    const int t = threadIdx.x;
    int o = 0;
    if (t < NBUCK) { o = btot[t]; sh[t] = o; }
    __syncthreads();
    for (int off = 1; off < NBUCK; off <<= 1) {
        int v = (t >= off && t < NBUCK) ? sh[t - off] : 0;
        __syncthreads();
        if (t < NBUCK) sh[t] += v;
        __syncthreads();
    }
    if (t < NBUCK) bbase[t] = sh[t] - o;
    if (t == NBUCK - 1) bbase[NBUCK] = sh[t];
}

// Pass 2: scatter edges into bucket regions; LDS running counters.
// payload: {src, e | ty<<21 | ldst<<23}
__global__ __launch_bounds__(256) void bucket_scatter_kernel(
    const int* __restrict__ src, const int* __restrict__ dst,
    const int* __restrict__ etype,
    const int* __restrict__ bhist, const int* __restrict__ bbase,
    int2* __restrict__ sc_bucket)
{
    __shared__ int cnt[NBUCK];
    const int t = threadIdx.x, b = blockIdx.x;
    for (int j = t; j < NBUCK; j += 256)
        cnt[j] = bbase[j] + bhist[b * NBUCK + j];
    __syncthreads();
    const int e0 = b * EPB;
    for (int i = t; i < EPB; i += 256) {
        const int e  = e0 + i;
        const int dn = dst[e];
        const int bu = dn / NPB;
        const int ld = dn - bu * NPB;
        const int slot = atomicAdd(&cnt[bu], 1);
        sc_bucket[slot] = make_int2(src[e], e | (etype[e] << 21) | (ld << 23));
    }
}

// Pass 3: one block per bucket: bin edges over 250 local nodes (LDS count/
// scan/scatter), emit ptr + final CSR {src, e | ty<<24}.
__global__ __launch_bounds__(256) void bucket_csr_kernel(
    const int2* __restrict__ sc_bucket, const int* __restrict__ bbase,
    int* __restrict__ ptr, int2* __restrict__ sc_csr)
{
    __shared__ int sdeg[256];
    __shared__ int scur[256];
    const int t = threadIdx.x, b = blockIdx.x;
    const int lo = bbase[b], hi = bbase[b + 1];
    const int count = hi - lo;

    sdeg[t] = 0;
    __syncthreads();
    for (int i = t; i < count; i += 256) {
        const int2 v = sc_bucket[lo + i];
        atomicAdd(&sdeg[(v.y >> 23) & 0xFF], 1);
    }
    __syncthreads();
    const int orig = sdeg[t];
    for (int off = 1; off < 256; off <<= 1) {
        const int v = (t >= off) ? sdeg[t - off] : 0;
        __syncthreads();
        sdeg[t] += v;
        __syncthreads();
    }
    const int excl = sdeg[t] - orig;
    if (t < NPB) ptr[b * NPB + t] = lo + excl;
    scur[t] = excl;
    if (b == 0 && t == 0) ptr[N_NODES] = N_EDGES;
    __syncthreads();
    for (int i = t; i < count; i += 256) {
        const int2 v = sc_bucket[lo + i];
        const int ld = (v.y >> 23) & 0xFF;
        const int slot = atomicAdd(&scur[ld], 1);
        sc_csr[lo + slot] = make_int2(v.x, (v.y & 0x1FFFFF) | (((v.y >> 21) & 3) << 24));
    }
}

// ---------------------------------------------------------------------------
// Kernel C: per-dst aggregation, one wave per node (unchanged from round 5).
// ---------------------------------------------------------------------------
__global__ __launch_bounds__(256) void agg_kernel(
    const int2* __restrict__ sc_csr, const int* __restrict__ ptr,
    const float* __restrict__ el, const float* __restrict__ er,
    const float* __restrict__ ee, const __hip_bfloat16* __restrict__ featb,
    float* __restrict__ rst, float* __restrict__ a_out)
{
    __shared__ float w_lds[4][MAXD_LDS * HEADS];
    const int wid  = threadIdx.x >> 6;
    const int lane = threadIdx.x & 63;
    const int n    = blockIdx.x * 4 + wid;

    const int p0  = ptr[n];
    const int deg = ptr[n + 1] - p0;
    float* wl = w_lds[wid];

    // ---- pass A ----
    const int hA = lane & 3;
    const int eo = lane >> 2;
    const float er_nA = er[n * HEADS + hA];
    const float ee0 = ee[0 * HEADS + hA];
    const float ee1 = ee[1 * HEADS + hA];
    const float ee2 = ee[2 * HEADS + hA];
    float zacc = 0.f;
    const bool fast = (deg <= MAXD_LDS);
    for (int base = 0; base < deg; base += 16) {
        const int idx = base + eo;
        if (idx < deg) {
            const int2 sc = sc_csr[p0 + idx];
            const int ty = sc.y >> 24;
            const float eeh = (ty == 0) ? ee0 : ((ty == 1) ? ee1 : ee2);
            float s = el[sc.x * HEADS + hA] + er_nA + eeh;
            s = s > 0.f ? s : NEG_SLOPE * s;
            const float wv = __expf(s);
            if (fast) wl[idx * HEADS + hA] = wv;
            zacc += wv;
        }
    }
#pragma unroll
    for (int m = 4; m < 64; m <<= 1) zacc += __shfl_xor(zacc, m, 64);

    // ---- pass B ----
    if (fast) {
        const int half  = lane >> 5;
        const int cpair = lane & 31;
        const int hB    = cpair >> 3;
        const float inv_z = (deg > 0) ? __frcp_rn(__shfl(zacc, hB, 64)) : 0.f;
        float rx = 0.f, ry = 0.f;
        int i = 0;
        for (; i + 4 <= deg; i += 4) {
            const int2 sc0 = sc_csr[p0 + i + half];
            const int2 sc1 = sc_csr[p0 + i + 2 + half];
            const uint f0 = *(const uint*)((const ushort*)featb + ((size_t)sc0.x << 6) + (cpair << 1));
            const uint f1 = *(const uint*)((const ushort*)featb + ((size_t)sc1.x << 6) + (cpair << 1));
            const float a0 = wl[(i + half) * HEADS + hB] * inv_z;
            const float a1 = wl[(i + 2 + half) * HEADS + hB] * inv_z;
            rx += __uint_as_float(f0 << 16) * a0;
            ry += __uint_as_float(f0 & 0xFFFF0000u) * a0;
            rx += __uint_as_float(f1 << 16) * a1;
            ry += __uint_as_float(f1 & 0xFFFF0000u) * a1;
            if ((lane & 7) == 0) {
                a_out[(size_t)(sc0.y & 0xFFFFFF) * HEADS + hB] = a0;
                a_out[(size_t)(sc1.y & 0xFFFFFF) * HEADS + hB] = a1;
            }
        }
        if (i + 2 <= deg) {
            const int2 sc0 = sc_csr[p0 + i + half];
            const uint f0 = *(const uint*)((const ushort*)featb + ((size_t)sc0.x << 6) + (cpair << 1));
            const float a0 = wl[(i + half) * HEADS + hB] * inv_z;
            rx += __uint_as_float(f0 << 16) * a0;
            ry += __uint_as_float(f0 & 0xFFFF0000u) * a0;
            if ((lane & 7) == 0)
                a_out[(size_t)(sc0.y & 0xFFFFFF) * HEADS + hB] = a0;
            i += 2;
        }
        if (i < deg) {
            const int2 sc0 = sc_csr[p0 + i];
            const uint f0 = *(const uint*)((const ushort*)featb + ((size_t)sc0.x << 6) + (cpair << 1));
            const float a0 = wl[i * HEADS + hB] * inv_z;
            if (half == 0) {
                rx += __uint_as_float(f0 << 16) * a0;
                ry += __uint_as_float(f0 & 0xFFFF0000u) * a0;
                if ((lane & 7) == 0)
                    a_out[(size_t)(sc0.y & 0xFFFFFF) * HEADS + hB] = a0;
            }
        }
        rx += __shfl_xor(rx, 32, 64);
        ry += __shfl_xor(ry, 32, 64);
        if (half == 0) {
            float2 v = make_float2(rx, ry);
            *(float2*)(rst + (size_t)n * HD + (cpair << 1)) = v;
        }
    } else {
        const int h = lane >> 4;
        const int d = lane & 15;
        const float inv_z = (deg > 0) ? __frcp_rn(__shfl(zacc, h, 64)) : 0.f;
        const float er_n = er[n * HEADS + h];
        const float g0 = ee[h], g1 = ee[HEADS + h], g2 = ee[2 * HEADS + h];
        float racc = 0.f;
        for (int i = 0; i < deg; ++i) {
            const int2 sc = sc_csr[p0 + i];
            const int ty = sc.y >> 24;
            const float eeh = (ty == 0) ? g0 : ((ty == 1) ? g1 : g2);
            float s = el[sc.x * HEADS + h] + er_n + eeh;
            s = s > 0.f ? s : NEG_SLOPE * s;
            const float a = __expf(s) * inv_z;
            racc += __bfloat162float(featb[(size_t)sc.x * HD + lane]) * a;
            if (d == 0) a_out[(size_t)(sc.y & 0xFFFFFF) * HEADS + h] = a;
        }
        rst[(size_t)n * HD + lane] = racc;
    }
}

extern "C" void kernel_launch(void* const* d_in, const int* in_sizes, int n_in,
                              void* d_out, int out_size, void* d_ws, size_t ws_size,
                              hipStream_t stream)
{
    const float* x        = (const float*)d_in[0];
    const float* W        = (const float*)d_in[1];
    const float* W_e      = (const float*)d_in[2];
    const float* attn_l   = (const float*)d_in[3];
    const float* attn_r   = (const float*)d_in[4];
    const float* attn_e   = (const float*)d_in[5];
    const float* edge_emb = (const float*)d_in[6];
    const int* src   = (const int*)d_in[7];
    const int* dst   = (const int*)d_in[8];
    const int* etype = (const int*)d_in[9];

    float* out     = (float*)d_out;
    float* rst_out = out;                              // N*H*D
    float* a_out   = out + (size_t)N_NODES * HD;       // E*H

    char* w = (char*)d_ws;
    __hip_bfloat16* featb = (__hip_bfloat16*)w; w += (size_t)N_NODES * HD * 2;   // 12.8 MB
    float* el    = (float*)w;  w += (size_t)N_NODES * HEADS * 4;    //  1.6 MB
    float* er    = (float*)w;  w += (size_t)N_NODES * HEADS * 4;    //  1.6 MB
    float* ee    = (float*)w;  w += 64;
    int*   ptr   = (int*)w;    w += (size_t)(N_NODES + 4) * 4;      //  0.4 MB
    int*   bhist = (int*)w;    w += (size_t)PBLK * NBUCK * 4;       //  0.64 MB
    int*   btot  = (int*)w;    w += (size_t)NBUCK * 4;
    int*   bbase = (int*)w;    w += (size_t)(NBUCK + 4) * 4;
    short* WTb   = (short*)w;  w += (size_t)HD * IN_FEATS * 2;      //   16 KB
    int2*  sc_bucket = (int2*)w; w += (size_t)N_EDGES * 8;          // 12.8 MB
    int2*  sc_csr    = (int2*)w; w += (size_t)N_EDGES * 8;          // 12.8 MB

    wt_prep_kernel<<<(IN_FEATS * HD) / 256, 256, 0, stream>>>(W, WTb);
    feat_el_er_kernel<<<N_NODES / 16, 256, 0, stream>>>(
        x, WTb, attn_l, attn_r, featb, el, er);
    ee_kernel<<<N_ETYPES * HEADS, 64, 0, stream>>>(edge_emb, W_e, attn_e, ee);

    bucket_hist_kernel<<<PBLK, 256, 0, stream>>>(dst, bhist);
    bucket_scan1_kernel<<<NBUCK, 256, 0, stream>>>(bhist, btot);
    bucket_scan2_kernel<<<1, 512, 0, stream>>>(btot, bbase);
    bucket_scatter_kernel<<<PBLK, 256, 0, stream>>>(src, dst, etype, bhist, bbase, sc_bucket);
    bucket_csr_kernel<<<NBUCK, 256, 0, stream>>>(sc_bucket, bbase, ptr, sc_csr);

    agg_kernel<<<N_NODES / 4, 256, 0, stream>>>(
        sc_csr, ptr, el, er, ee, featb, rst_out, a_out);
}

// Round 7
// 290.580 us; speedup vs baseline: 21.1628x; 1.0474x over previous
//
#include <hip/hip_runtime.h>
#include <hip/hip_bf16.h>

#define N_NODES   100000
#define N_EDGES   1600000
#define N_ETYPES  3
#define IN_FEATS  128
#define HEADS     4
#define OUT_FEATS 16
#define EDGE_FEATS 64
#define HD        64            // HEADS*OUT_FEATS
#define NEG_SLOPE 0.2f
#define MAXD_LDS  128           // agg fast-path max degree (Poisson(16): P(>128)~0)

#define NBUCK     800           // buckets for counting sort
#define NPB       125           // nodes per bucket (800*125 = N_NODES)
#define PBLK      400           // blocks in hist/scatter passes
#define EPB       4000          // edges per block (400*4000 = N_EDGES)
#define BCAP      2560          // LDS stage capacity in bucket_csr (mean 2000, std ~45)

typedef short s16x8 __attribute__((ext_vector_type(8)));
typedef float f32x4 __attribute__((ext_vector_type(4)));

__device__ __forceinline__ short f2bs(float f) {
    __hip_bfloat16 h = __float2bfloat16(f);
    return *reinterpret_cast<short*>(&h);
}

// ---------------------------------------------------------------------------
// Prep: WT bf16 [64][128]  (WT[n][k] = W[k][n])
// ---------------------------------------------------------------------------
__global__ __launch_bounds__(256) void wt_prep_kernel(
    const float* __restrict__ W, short* __restrict__ WTb)
{
    const int t = blockIdx.x * 256 + threadIdx.x;   // 0..8191
    const int k = t >> 6, n = t & 63;
    WTb[n * IN_FEATS + k] = f2bs(W[t]);
}

// ---------------------------------------------------------------------------
// Kernel A (MFMA): feat = x @ W, bf16 store, fused el/er.
// ---------------------------------------------------------------------------
#define XS_STRIDE 136   // 128 + 8 pad shorts
__global__ __launch_bounds__(256) void feat_el_er_kernel(
    const float* __restrict__ x,
    const short* __restrict__ WTb,
    const float* __restrict__ attn_l,
    const float* __restrict__ attn_r,
    __hip_bfloat16* __restrict__ featb,
    float* __restrict__ el,
    float* __restrict__ er)
{
    __shared__ short Xs[16 * XS_STRIDE];
    __shared__ short Ws[64 * XS_STRIDE];

    const int t = threadIdx.x;
    const int row0 = blockIdx.x * 16;
    {   // stage x -> bf16 LDS
        const int r = t >> 4, k0 = (t & 15) * 8;
        const float4* xg = (const float4*)(x + (size_t)(row0 + r) * IN_FEATS + k0);
        const float4 v0 = xg[0], v1 = xg[1];
        s16x8 p;
        p[0] = f2bs(v0.x); p[1] = f2bs(v0.y); p[2] = f2bs(v0.z); p[3] = f2bs(v0.w);
        p[4] = f2bs(v1.x); p[5] = f2bs(v1.y); p[6] = f2bs(v1.z); p[7] = f2bs(v1.w);
        *(s16x8*)&Xs[r * XS_STRIDE + k0] = p;
    }
    {   // stage WT bf16
#pragma unroll
        for (int j = 0; j < 4; ++j) {
            const int u = t + 256 * j;
            const int r = u >> 4, c = (u & 15) * 8;
            *(s16x8*)&Ws[r * XS_STRIDE + c] = *(const s16x8*)(WTb + r * IN_FEATS + c);
        }
    }
    __syncthreads();

    const int w    = t >> 6;
    const int lane = t & 63;
    const int m    = lane & 15;
    const int q    = lane >> 4;

    f32x4 acc = {0.f, 0.f, 0.f, 0.f};
#pragma unroll
    for (int kb = 0; kb < 4; ++kb) {
        const s16x8 af = *(const s16x8*)&Xs[m * XS_STRIDE + kb * 32 + q * 8];
        const s16x8 bf = *(const s16x8*)&Ws[(w * 16 + m) * XS_STRIDE + kb * 32 + q * 8];
        acc = __builtin_amdgcn_mfma_f32_16x16x32_bf16(af, bf, acc, 0, 0, 0);
    }

    const float al = attn_l[w * OUT_FEATS + m];
    const float ar = attn_r[w * OUT_FEATS + m];
#pragma unroll
    for (int r = 0; r < 4; ++r) {
        const int row = row0 + q * 4 + r;
        featb[(size_t)row * HD + w * 16 + m] = __float2bfloat16(acc[r]);
        float cl = acc[r] * al;
        float cr = acc[r] * ar;
#pragma unroll
        for (int msk = 1; msk < 16; msk <<= 1) {
            cl += __shfl_xor(cl, msk, 64);
            cr += __shfl_xor(cr, msk, 64);
        }
        if (m == 0) {
            el[row * HEADS + w] = cl;
            er[row * HEADS + w] = cr;
        }
    }
}

// ---------------------------------------------------------------------------
// Kernel B: ee[t,h] (12 scalars)
// ---------------------------------------------------------------------------
__global__ __launch_bounds__(64) void ee_kernel(
    const float* __restrict__ edge_emb,
    const float* __restrict__ W_e,
    const float* __restrict__ attn_e,
    float* __restrict__ ee)
{
    const int b  = blockIdx.x;
    const int ty = b >> 2;
    const int h  = b & 3;
    const int e  = threadIdx.x;

    float ef = 0.f;
#pragma unroll
    for (int k = 0; k < EDGE_FEATS; ++k)
        ef += edge_emb[ty * EDGE_FEATS + k] *
              W_e[k * (HEADS * EDGE_FEATS) + h * EDGE_FEATS + e];
    float v = ef * attn_e[h * EDGE_FEATS + e];
#pragma unroll
    for (int m = 1; m < 64; m <<= 1) v += __shfl_xor(v, m, 64);
    if (e == 0) ee[ty * HEADS + h] = v;
}

// ---------------------------------------------------------------------------
// CSR build via bucketed counting sort — all hot atomics in LDS.
// ---------------------------------------------------------------------------
__global__ __launch_bounds__(256) void bucket_hist_kernel(
    const int* __restrict__ dst, int* __restrict__ bhist)
{
    __shared__ int h[NBUCK];
    const int t = threadIdx.x, b = blockIdx.x;
    for (int j = t; j < NBUCK; j += 256) h[j] = 0;
    __syncthreads();
    const int e0 = b * EPB;
    for (int i = t; i < EPB; i += 256)
        atomicAdd(&h[dst[e0 + i] / NPB], 1);
    __syncthreads();
    for (int j = t; j < NBUCK; j += 256) bhist[b * NBUCK + j] = h[j];
}

// per bucket j, exclusive scan over blocks; btot[j] = total.
__global__ __launch_bounds__(256) void bucket_scan1_kernel(
    int* __restrict__ bhist, int* __restrict__ btot)
{
    __shared__ int sh[PBLK];
    const int t = threadIdx.x, j = blockIdx.x;
    const int j0 = t, j1 = t + 256;
    int o0 = 0, o1 = 0;
    if (j0 < PBLK) { o0 = bhist[j0 * NBUCK + j]; sh[j0] = o0; }
    if (j1 < PBLK) { o1 = bhist[j1 * NBUCK + j]; sh[j1] = o1; }
    __syncthreads();
    for (int off = 1; off < PBLK; off <<= 1) {
        int v0 = (j0 >= off && j0 < PBLK) ? sh[j0 - off] : 0;
        int v1 = (j1 >= off && j1 < PBLK) ? sh[j1 - off] : 0;
        __syncthreads();
        if (j0 < PBLK) sh[j0] += v0;
        if (j1 < PBLK) sh[j1] += v1;
        __syncthreads();
    }
    if (j0 < PBLK) bhist[j0 * NBUCK + j] = sh[j0] - o0;
    if (j1 < PBLK) bhist[j1 * NBUCK + j] = sh[j1] - o1;
    if (t == 255) btot[j] = sh[PBLK - 1];
}

// single block: exclusive scan btot[NBUCK] -> bbase[NBUCK+1]
__global__ __launch_bounds__(1024) void bucket_scan2_kernel(
    const int* __restrict__ btot, int* __restrict__ bbase)
{
    __shared__ int sh[NBUCK];
    const int t = threadIdx.x;
    int o = 0;
    if (t < NBUCK) { o = btot[t]; sh[t] = o; }
    __syncthreads();
    for (int off = 1; off < NBUCK; off <<= 1) {
        int v = (t >= off && t < NBUCK) ? sh[t - off] : 0;
        __syncthreads();
        if (t < NBUCK) sh[t] += v;
        __syncthreads();
    }
    if (t < NBUCK) bbase[t] = sh[t] - o;
    if (t == NBUCK - 1) bbase[NBUCK] = sh[t];
}

// scatter edges into bucket regions; LDS running counters.
// payload: {src, e | ty<<21 | ldst<<23}  (e:21b, ty:2b, ldst:7b)
__global__ __launch_bounds__(256) void bucket_scatter_kernel(
    const int* __restrict__ src, const int* __restrict__ dst,
    const int* __restrict__ etype,
    const int* __restrict__ bhist, const int* __restrict__ bbase,
    int2* __restrict__ sc_bucket)
{
    __shared__ int cnt[NBUCK];
    const int t = threadIdx.x, b = blockIdx.x;
    for (int j = t; j < NBUCK; j += 256)
        cnt[j] = bbase[j] + bhist[b * NBUCK + j];
    __syncthreads();
    const int e0 = b * EPB;
    for (int i = t; i < EPB; i += 256) {
        const int e  = e0 + i;
        const int dn = dst[e];
        const int bu = dn / NPB;
        const int ld = dn - bu * NPB;
        const int slot = atomicAdd(&cnt[bu], 1);
        sc_bucket[slot] = make_int2(src[e], e | (etype[e] << 21) | (ld << 23));
    }
}

// one block per bucket: LDS-stage edges (single global read), bin over 125
// local nodes in LDS, emit ptr + final CSR {src, e | ty<<24}.
__global__ __launch_bounds__(256) void bucket_csr_kernel(
    const int2* __restrict__ sc_bucket, const int* __restrict__ bbase,
    int* __restrict__ ptr, int2* __restrict__ sc_csr)
{
    __shared__ int2 sbuf[BCAP];      // 20.5 KB
    __shared__ int sdeg[128];
    __shared__ int scur[128];
    const int t = threadIdx.x, b = blockIdx.x;
    const int lo = bbase[b];
    const int count = bbase[b + 1] - lo;
    const bool staged = (count <= BCAP);

    if (t < 128) sdeg[t] = 0;
    __syncthreads();
    if (staged) {
        for (int i = t; i < count; i += 256) {
            const int2 v = sc_bucket[lo + i];
            sbuf[i] = v;
            atomicAdd(&sdeg[(v.y >> 23) & 0x7F], 1);
        }
    } else {
        for (int i = t; i < count; i += 256)
            atomicAdd(&sdeg[(sc_bucket[lo + i].y >> 23) & 0x7F], 1);
    }
    __syncthreads();
    // exclusive scan over 128 (125 used)
    const int orig = (t < 128) ? sdeg[t] : 0;
    for (int off = 1; off < 128; off <<= 1) {
        const int v = (t < 128 && t >= off) ? sdeg[t - off] : 0;
        __syncthreads();
        if (t < 128) sdeg[t] += v;
        __syncthreads();
    }
    if (t < 128) {
        const int excl = sdeg[t] - orig;
        if (t < NPB) ptr[b * NPB + t] = lo + excl;
        scur[t] = lo + excl;             // global slot base
    }
    if (b == 0 && t == 0) ptr[N_NODES] = N_EDGES;
    __syncthreads();
    if (staged) {
        for (int i = t; i < count; i += 256) {
            const int2 v = sbuf[i];
            const int ld = (v.y >> 23) & 0x7F;
            const int slot = atomicAdd(&scur[ld], 1);
            sc_csr[slot] = make_int2(v.x, (v.y & 0x1FFFFF) | (((v.y >> 21) & 3) << 24));
        }
    } else {
        for (int i = t; i < count; i += 256) {
            const int2 v = sc_bucket[lo + i];
            const int ld = (v.y >> 23) & 0x7F;
            const int slot = atomicAdd(&scur[ld], 1);
            sc_csr[slot] = make_int2(v.x, (v.y & 0x1FFFFF) | (((v.y >> 21) & 3) << 24));
        }
    }
}

// ---------------------------------------------------------------------------
// Kernel C: per-dst aggregation, one wave per node, SINGLE PASS.
// rst = (sum_e w_e * feat[src_e]) * inv_z  — normalization commutes.
// Half-wave per edge (lane = 2 cols), w stashed in LDS for a_out epilogue.
// ---------------------------------------------------------------------------
__global__ __launch_bounds__(256) void agg_kernel(
    const int2* __restrict__ sc_csr, const int* __restrict__ ptr,
    const float* __restrict__ el, const float* __restrict__ er,
    const float* __restrict__ ee, const __hip_bfloat16* __restrict__ featb,
    float* __restrict__ rst, float* __restrict__ a_out)
{
    __shared__ float w_lds[4][MAXD_LDS * HEADS];   // 8 KB
    const int wid  = threadIdx.x >> 6;
    const int lane = threadIdx.x & 63;
    const int n    = blockIdx.x * 4 + wid;

    const int p0  = ptr[n];
    const int deg = ptr[n + 1] - p0;
    float* wl = w_lds[wid];
    const ushort* fb = (const ushort*)featb;

    if (deg <= MAXD_LDS) {
        // ---- fast path: single fused pass ----
        const int half  = lane >> 5;          // which edge of the pair
        const int cpair = lane & 31;          // cols 2*cpair, 2*cpair+1
        const int hB    = cpair >> 3;         // head of both cols
        const bool accL = (cpair & 7) == 0;   // 1 lane per (edge-half, head)
        const float er_n = er[n * HEADS + hB];
        const float g0 = ee[hB], g1 = ee[HEADS + hB], g2 = ee[2 * HEADS + hB];

        float zacc = 0.f, rx = 0.f, ry = 0.f;
        int i = 0;
        for (; i + 4 <= deg; i += 4) {
            const int2 sc0 = sc_csr[p0 + i + half];
            const int2 sc1 = sc_csr[p0 + i + 2 + half];
            const uint f0 = *(const uint*)(fb + ((size_t)sc0.x << 6) + (cpair << 1));
            const uint f1 = *(const uint*)(fb + ((size_t)sc1.x << 6) + (cpair << 1));
            const float el0 = el[sc0.x * HEADS + hB];
            const float el1 = el[sc1.x * HEADS + hB];
            const int ty0 = sc0.y >> 24, ty1 = sc1.y >> 24;
            float s0 = el0 + er_n + ((ty0 == 0) ? g0 : ((ty0 == 1) ? g1 : g2));
            float s1 = el1 + er_n + ((ty1 == 0) ? g0 : ((ty1 == 1) ? g1 : g2));
            s0 = s0 > 0.f ? s0 : NEG_SLOPE * s0;
            s1 = s1 > 0.f ? s1 : NEG_SLOPE * s1;
            const float w0 = __expf(s0), w1 = __expf(s1);
            if (accL) {
                zacc += w0 + w1;
                wl[(i + half) * HEADS + hB]     = w0;
                wl[(i + 2 + half) * HEADS + hB] = w1;
            }
            rx += __uint_as_float(f0 << 16) * w0 + __uint_as_float(f1 << 16) * w1;
            ry += __uint_as_float(f0 & 0xFFFF0000u) * w0 + __uint_as_float(f1 & 0xFFFF0000u) * w1;
        }
        if (i + 2 <= deg) {
            const int2 sc0 = sc_csr[p0 + i + half];
            const uint f0 = *(const uint*)(fb + ((size_t)sc0.x << 6) + (cpair << 1));
            const float el0 = el[sc0.x * HEADS + hB];
            const int ty0 = sc0.y >> 24;
            float s0 = el0 + er_n + ((ty0 == 0) ? g0 : ((ty0 == 1) ? g1 : g2));
            s0 = s0 > 0.f ? s0 : NEG_SLOPE * s0;
            const float w0 = __expf(s0);
            if (accL) {
                zacc += w0;
                wl[(i + half) * HEADS + hB] = w0;
            }
            rx += __uint_as_float(f0 << 16) * w0;
            ry += __uint_as_float(f0 & 0xFFFF0000u) * w0;
            i += 2;
        }
        if (i < deg) {                         // odd tail: half 0 only
            if (half == 0) {
                const int2 sc0 = sc_csr[p0 + i];
                const uint f0 = *(const uint*)(fb + ((size_t)sc0.x << 6) + (cpair << 1));
                const float el0 = el[sc0.x * HEADS + hB];
                const int ty0 = sc0.y >> 24;
                float s0 = el0 + er_n + ((ty0 == 0) ? g0 : ((ty0 == 1) ? g1 : g2));
                s0 = s0 > 0.f ? s0 : NEG_SLOPE * s0;
                const float w0 = __expf(s0);
                if (accL) {
                    zacc += w0;
                    wl[i * HEADS + hB] = w0;
                }
                rx += __uint_as_float(f0 << 16) * w0;
                ry += __uint_as_float(f0 & 0xFFFF0000u) * w0;
            }
        }
        // reduce z across halves; lanes 8h hold z for head h
        zacc += __shfl_xor(zacc, 32, 64);
        const float inv_z = (deg > 0) ? __frcp_rn(__shfl(zacc, hB << 3, 64)) : 0.f;

        rx += __shfl_xor(rx, 32, 64);
        ry += __shfl_xor(ry, 32, 64);
        if (half == 0) {
            float2 v = make_float2(rx * inv_z, ry * inv_z);
            *(float2*)(rst + (size_t)n * HD + (cpair << 1)) = v;
        }
        // a_out epilogue: layout (eo = lane>>2, hA = lane&3); sc_csr is L1-hot
        const int hA = lane & 3;
        const int eo = lane >> 2;
        const float inv_zA = (deg > 0) ? __frcp_rn(__shfl(zacc, hA << 3, 64)) : 0.f;
        for (int idx = eo; idx < deg; idx += 16) {
            const int ey = sc_csr[p0 + idx].y & 0xFFFFFF;
            a_out[(size_t)ey * HEADS + hA] = wl[idx * HEADS + hA] * inv_zA;
        }
    } else {
        // ---- rare big-degree path: two passes, recompute ----
        const int hA = lane & 3;
        const int eo = lane >> 2;
        const float er_nA = er[n * HEADS + hA];
        const float a0 = ee[hA], a1 = ee[HEADS + hA], a2 = ee[2 * HEADS + hA];
        float zacc = 0.f;
        for (int base = 0; base < deg; base += 16) {
            const int idx = base + eo;
            if (idx < deg) {
                const int2 sc = sc_csr[p0 + idx];
                const int ty = sc.y >> 24;
                float s = el[sc.x * HEADS + hA] + er_nA + ((ty == 0) ? a0 : ((ty == 1) ? a1 : a2));
                s = s > 0.f ? s : NEG_SLOPE * s;
                zacc += __expf(s);
            }
        }
#pragma unroll
        for (int m = 4; m < 64; m <<= 1) zacc += __shfl_xor(zacc, m, 64);
        const int h = lane >> 4;
        const int d = lane & 15;
        const float inv_z = __frcp_rn(__shfl(zacc, h, 64));
        const float er_n = er[n * HEADS + h];
        const float g0 = ee[h], g1 = ee[HEADS + h], g2 = ee[2 * HEADS + h];
        float racc = 0.f;
        for (int i = 0; i < deg; ++i) {
            const int2 sc = sc_csr[p0 + i];
            const int ty = sc.y >> 24;
            float s = el[sc.x * HEADS + h] + er_n + ((ty == 0) ? g0 : ((ty == 1) ? g1 : g2));
            s = s > 0.f ? s : NEG_SLOPE * s;
            const float a = __expf(s) * inv_z;
            racc += __bfloat162float(featb[(size_t)sc.x * HD + lane]) * a;
            if (d == 0) a_out[(size_t)(sc.y & 0xFFFFFF) * HEADS + h] = a;
        }
        rst[(size_t)n * HD + lane] = racc;
    }
}

extern "C" void kernel_launch(void* const* d_in, const int* in_sizes, int n_in,
                              void* d_out, int out_size, void* d_ws, size_t ws_size,
                              hipStream_t stream)
{
    const float* x        = (const float*)d_in[0];
    const float* W        = (const float*)d_in[1];
    const float* W_e      = (const float*)d_in[2];
    const float* attn_l   = (const float*)d_in[3];
    const float* attn_r   = (const float*)d_in[4];
    const float* attn_e   = (const float*)d_in[5];
    const float* edge_emb = (const float*)d_in[6];
    const int* src   = (const int*)d_in[7];
    const int* dst   = (const int*)d_in[8];
    const int* etype = (const int*)d_in[9];

    float* out     = (float*)d_out;
    float* rst_out = out;                              // N*H*D
    float* a_out   = out + (size_t)N_NODES * HD;       // E*H

    char* w = (char*)d_ws;
    __hip_bfloat16* featb = (__hip_bfloat16*)w; w += (size_t)N_NODES * HD * 2;   // 12.8 MB
    float* el    = (float*)w;  w += (size_t)N_NODES * HEADS * 4;    //  1.6 MB
    float* er    = (float*)w;  w += (size_t)N_NODES * HEADS * 4;    //  1.6 MB
    float* ee    = (float*)w;  w += 64;
    int*   ptr   = (int*)w;    w += (size_t)(N_NODES + 4) * 4;      //  0.4 MB
    int*   bhist = (int*)w;    w += (size_t)PBLK * NBUCK * 4;       //  1.28 MB
    int*   btot  = (int*)w;    w += (size_t)NBUCK * 4;
    int*   bbase = (int*)w;    w += (size_t)(NBUCK + 4) * 4;
    short* WTb   = (short*)w;  w += (size_t)HD * IN_FEATS * 2;      //   16 KB
    int2*  sc_bucket = (int2*)w; w += (size_t)N_EDGES * 8;          // 12.8 MB
    int2*  sc_csr    = (int2*)w; w += (size_t)N_EDGES * 8;          // 12.8 MB

    wt_prep_kernel<<<(IN_FEATS * HD) / 256, 256, 0, stream>>>(W, WTb);
    feat_el_er_kernel<<<N_NODES / 16, 256, 0, stream>>>(
        x, WTb, attn_l, attn_r, featb, el, er);
    ee_kernel<<<N_ETYPES * HEADS, 64, 0, stream>>>(edge_emb, W_e, attn_e, ee);

    bucket_hist_kernel<<<PBLK, 256, 0, stream>>>(dst, bhist);
    bucket_scan1_kernel<<<NBUCK, 256, 0, stream>>>(bhist, btot);
    bucket_scan2_kernel<<<1, 1024, 0, stream>>>(btot, bbase);
    bucket_scatter_kernel<<<PBLK, 256, 0, stream>>>(src, dst, etype, bhist, bbase, sc_bucket);
    bucket_csr_kernel<<<NBUCK, 256, 0, stream>>>(sc_bucket, bbase, ptr, sc_csr);

    agg_kernel<<<N_NODES / 4, 256, 0, stream>>>(
        sc_csr, ptr, el, er, ee, featb, rst_out, a_out);
}